// Round 2
// baseline (528.389 us; speedup 1.0000x reference)
//
#include <hip/hip_runtime.h>

typedef _Float16 h4 __attribute__((ext_vector_type(4)));
typedef _Float16 h8 __attribute__((ext_vector_type(8)));
typedef float f4 __attribute__((ext_vector_type(4)));
typedef int i4 __attribute__((ext_vector_type(4)));

#define CIN 256
#define HID 256
#define HWSZ 16384
#define NT 64

// Pack W1^T and W2 into f16 MFMA fragment order (A-frag and B-frag index
// formulas are identical: lane li indexes the non-K dim, quad*8+j indexes K).
// fi(m,k) = (k>>5)<<13 | (m>>4)<<9 | ((k>>3)&3)<<7 | (m&15)<<3 | (k&7)
__global__ __launch_bounds__(256) void wconv_kernel(const float* __restrict__ W1,
                                                    const float* __restrict__ W2,
                                                    _Float16* __restrict__ W1f,
                                                    _Float16* __restrict__ W2f) {
  int t = blockIdx.x * 256 + threadIdx.x;  // 0..65535
  int m = t & 255;                          // non-K index (d for W1, c for W2)
  int k = t >> 8;                           // K index     (c for W1, d for W2)
  int fi = ((k >> 5) << 13) | ((m >> 4) << 9) | (((k >> 3) & 3) << 7) |
           ((m & 15) << 3) | (k & 7);
  W1f[fi] = (_Float16)W1[k * 256 + m];  // A1[d][c] = W1[c][d]  (GEMM1 A-operand)
  W2f[fi] = (_Float16)W2[k * 256 + m];  // B2[d][c] = W2[d][c]  (GEMM2 B-operand)
}

// Single 32 KB LDS buffer: holds X (f16, [n][c], xor-swizzled), then H ([n][d]).
// GEMM1: Hd = relu(W1^T X + b1): A=W1f (global), B=X (LDS);  D rows=d, cols=n.
// GEMM2: Y  = H W2 + b2:         A=H (LDS),    B=W2f (global); D rows=n, cols=c
//   -> each lane holds 4 consecutive pixels per channel => dwordx4 stores.
__global__ __launch_bounds__(256, 4) void mlp_kernel(
    const float* __restrict__ in, const int* __restrict__ mask,
    const float* __restrict__ b1, const float* __restrict__ b2,
    const _Float16* __restrict__ W1f, const _Float16* __restrict__ W2f,
    float* __restrict__ out) {
  __shared__ alignas(16) _Float16 S[NT * 256];  // 32 KB, X then H

  const int t = threadIdx.x;
  const int g = blockIdx.x;
  const int b = g >> 8;              // 256 tiles per batch image
  const int hw0 = (g & 255) * NT;
  const float* inb = in + (size_t)b * CIN * HWSZ + hw0;

  // ---- stage X (fp32 global -> f16 LDS [n][c], swizzled) ----
  {
    const int n = t & 63;
    const int cg = (t >> 6) * 4;
    const int sw = (n & 7) << 3;
#pragma unroll
    for (int i = 0; i < 16; ++i) {
      const int c0 = i * 16 + cg;
      float x0 = inb[(size_t)(c0 + 0) * HWSZ + n];
      float x1 = inb[(size_t)(c0 + 1) * HWSZ + n];
      float x2 = inb[(size_t)(c0 + 2) * HWSZ + n];
      float x3 = inb[(size_t)(c0 + 3) * HWSZ + n];
      h4 xv;
      xv[0] = (_Float16)x0; xv[1] = (_Float16)x1;
      xv[2] = (_Float16)x2; xv[3] = (_Float16)x3;
      *(h4*)&S[n * 256 + (c0 ^ sw)] = xv;
    }
  }
  __syncthreads();

  const int w = t >> 6;     // wave 0..3
  const int l = t & 63;
  const int li = l & 15;
  const int q = l >> 4;
  const int swl = (li & 7) << 3;

  f4 acc[4][4];
#pragma unroll
  for (int mt = 0; mt < 4; ++mt)
#pragma unroll
    for (int nt = 0; nt < 4; ++nt)
#pragma unroll
      for (int r = 0; r < 4; ++r) acc[mt][nt][r] = 0.f;

  // ---- GEMM1: wave w owns d-range [64w,64w+64); tiles: mt=d, nt=n ----
#pragma unroll 2
  for (int kc = 0; kc < 8; ++kc) {
    h8 af[4], bf[4];
#pragma unroll
    for (int mt = 0; mt < 4; ++mt)
      af[mt] = *(const h8*)(W1f + (kc << 13) + ((4 * w + mt) << 9) + (l << 3));
#pragma unroll
    for (int nt = 0; nt < 4; ++nt)
      bf[nt] = *(const h8*)&S[(nt * 16 + li) * 256 + (((kc << 5) + (q << 3)) ^ swl)];
#pragma unroll
    for (int mt = 0; mt < 4; ++mt)
#pragma unroll
      for (int nt = 0; nt < 4; ++nt)
        acc[mt][nt] = __builtin_amdgcn_mfma_f32_16x16x32_f16(af[mt], bf[nt], acc[mt][nt], 0, 0, 0);
  }
  __syncthreads();  // all X reads done; S may be overwritten with H

  // ---- epilogue 1: bias + relu -> S[n][d] (b64 writes, lane has 4 consecutive d) ----
#pragma unroll
  for (int mt = 0; mt < 4; ++mt) {
    const int d0 = w * 64 + mt * 16 + q * 4;
    const f4 bb = *(const f4*)(b1 + d0);
#pragma unroll
    for (int nt = 0; nt < 4; ++nt) {
      const int nn = nt * 16 + li;
      h4 hv;
#pragma unroll
      for (int r = 0; r < 4; ++r) {
        float v = acc[mt][nt][r] + bb[r];
        hv[r] = (_Float16)(v > 0.f ? v : 0.f);
      }
      *(h4*)&S[nn * 256 + (d0 ^ swl)] = hv;
    }
  }
  __syncthreads();

  // ---- GEMM2: wave w owns c-range [64w,64w+64); tiles: mt=n, nt=c ----
#pragma unroll
  for (int mt = 0; mt < 4; ++mt)
#pragma unroll
    for (int nt = 0; nt < 4; ++nt)
#pragma unroll
      for (int r = 0; r < 4; ++r) acc[mt][nt][r] = 0.f;

#pragma unroll 2
  for (int kc = 0; kc < 8; ++kc) {
    h8 af[4], bf[4];
#pragma unroll
    for (int mt = 0; mt < 4; ++mt)
      af[mt] = *(const h8*)&S[(mt * 16 + li) * 256 + (((kc << 5) + (q << 3)) ^ swl)];
#pragma unroll
    for (int nt = 0; nt < 4; ++nt)
      bf[nt] = *(const h8*)(W2f + (kc << 13) + ((4 * w + nt) << 9) + (l << 3));
#pragma unroll
    for (int mt = 0; mt < 4; ++mt)
#pragma unroll
      for (int nt = 0; nt < 4; ++nt)
        acc[mt][nt] = __builtin_amdgcn_mfma_f32_16x16x32_f16(af[mt], bf[nt], acc[mt][nt], 0, 0, 0);
  }

  // ---- epilogue 2: bias + mask select, vectorized along pixels ----
  const int* mb = mask + b * HWSZ + hw0;
  i4 m4[4];
#pragma unroll
  for (int mt = 0; mt < 4; ++mt) m4[mt] = *(const i4*)&mb[mt * 16 + q * 4];
  float b2v[4];
#pragma unroll
  for (int nt = 0; nt < 4; ++nt) b2v[nt] = b2[w * 64 + nt * 16 + li];

  float* outb = out + (size_t)b * CIN * HWSZ + hw0;
#pragma unroll
  for (int mt = 0; mt < 4; ++mt) {
    const int n0 = mt * 16 + q * 4;
    f4 xv[4];
#pragma unroll
    for (int nt = 0; nt < 4; ++nt) {
      const size_t off = (size_t)(w * 64 + nt * 16 + li) * HWSZ + n0;
      xv[nt] = *(const f4*)&inb[off];
    }
#pragma unroll
    for (int nt = 0; nt < 4; ++nt) {
      const size_t off = (size_t)(w * 64 + nt * 16 + li) * HWSZ + n0;
      f4 y;
#pragma unroll
      for (int r = 0; r < 4; ++r)
        y[r] = m4[mt][r] ? (acc[mt][nt][r] + b2v[nt]) : xv[nt][r];
      *(f4*)&outb[off] = y;
    }
  }
}

extern "C" void kernel_launch(void* const* d_in, const int* in_sizes, int n_in,
                              void* d_out, int out_size, void* d_ws, size_t ws_size,
                              hipStream_t stream) {
  const float* in = (const float*)d_in[0];
  const int* mask = (const int*)d_in[1];
  const float* W1 = (const float*)d_in[2];
  const float* b1 = (const float*)d_in[3];
  const float* W2 = (const float*)d_in[4];
  const float* b2 = (const float*)d_in[5];
  float* out = (float*)d_out;

  _Float16* W1f = (_Float16*)d_ws;              // 128 KB
  _Float16* W2f = W1f + 65536;                  // 128 KB

  hipLaunchKernelGGL(wconv_kernel, dim3(256), dim3(256), 0, stream, W1, W2, W1f, W2f);
  hipLaunchKernelGGL(mlp_kernel, dim3(16 * (HWSZ / NT)), dim3(256), 0, stream,
                     in, mask, b1, b2, W1f, W2f, out);
}